// Round 7
// baseline (54.759 us; speedup 1.0000x reference)
//
#include <hip/hip_runtime.h>

#define NV 2048
#define BS 16
#define NC 16

#define TOTAL_F 67108864LL          // 16 * 2048 * 2048
#define NBLK 2048
#define F4_PER_BLOCK 8192           // contiguous float4s per block (128 KB = 16 rows)

typedef float fx4 __attribute__((ext_vector_type(4)));

// Block bid covers batch (bid>>7), rows (bid&127)*16 .. +16, all 2048 cols.
// Iteration i covers row (i>>1), half (i&1): cols [(i&1)*1024 + t*4 ..+4).
// Corner (target can be 1): rows<256 -> (bid&127)<16; cols<256 -> i even, t<64.
//
// Single-kernel design: block partials are pre-scaled by 1/TOTAL and
// atomicAdd'ed into d_out[0], which a 4-byte async memset zeroes per call.
// (Cross-replay L3 reuse is impossible: harness restore-fills write ~1 GB
// between replays, scrubbing the 256 MiB Infinity Cache. HBM-bound.)

__global__ __launch_bounds__(256) void k_main(const float* __restrict__ x,
                                              const int* __restrict__ cs,
                                              float* __restrict__ out) {
    int bid = blockIdx.x;
    int t = threadIdx.x;
    const fx4* x4 = (const fx4*)x + (long long)bid * F4_PER_BLOCK;

    bool corner = (bid & 127) < 16;
    float s = 0.f;

    if (!corner) {
        // ---- pure stream: 8-deep load batches, 8 independent accumulators ----
        float a[8] = {0.f, 0.f, 0.f, 0.f, 0.f, 0.f, 0.f, 0.f};
#pragma unroll
        for (int g = 0; g < 4; ++g) {
            fx4 v[8];
#pragma unroll
            for (int u = 0; u < 8; ++u)
                v[u] = x4[(g * 8 + u) * 256 + t];
#pragma unroll
            for (int u = 0; u < 8; ++u)
                a[u] += v[u].x * v[u].x + v[u].y * v[u].y + v[u].z * v[u].z + v[u].w * v[u].w;
        }
        s = ((a[0] + a[1]) + (a[2] + a[3])) + ((a[4] + a[5]) + (a[6] + a[7]));
    } else {
        // ---- corner block: stream + inline correction from registers ----
        int b = bid >> 7;
        int r0 = (bid & 127) << 4;              // < 256
        __shared__ int st_[NC], en_[NC];
        __shared__ unsigned rowm[16];
        if (t < NC) {
            int sz = cs[b * NC + t];
            int st = (t == 0) ? 0 : cs[b * NC + t - 1];  // start_k = n_{k-1} (NOT cumulative)
            st_[t] = st;
            en_[t] = st + sz;
        }
        __syncthreads();
        if (t < 16) {
            int r = r0 + t;
            unsigned m = 0;
#pragma unroll
            for (int k = 0; k < NC; ++k)
                if (r >= st_[k] && r < en_[k]) m |= 1u << k;
            rowm[t] = m;
        }
        unsigned cm0 = 0, cm1 = 0, cm2 = 0, cm3 = 0;
        if (t < 64) {
            int c = t * 4;
#pragma unroll
            for (int k = 0; k < NC; ++k) {
                int st = st_[k], en = en_[k];
                if (c     >= st && c     < en) cm0 |= 1u << k;
                if (c + 1 >= st && c + 1 < en) cm1 |= 1u << k;
                if (c + 2 >= st && c + 2 < en) cm2 |= 1u << k;
                if (c + 3 >= st && c + 3 < en) cm3 |= 1u << k;
            }
        }
        __syncthreads();

        float a[8] = {0.f, 0.f, 0.f, 0.f, 0.f, 0.f, 0.f, 0.f};
#pragma unroll
        for (int g = 0; g < 4; ++g) {
            fx4 v[8];
#pragma unroll
            for (int u = 0; u < 8; ++u)
                v[u] = x4[(g * 8 + u) * 256 + t];
#pragma unroll
            for (int u = 0; u < 8; ++u)
                a[u] += v[u].x * v[u].x + v[u].y * v[u].y + v[u].z * v[u].z + v[u].w * v[u].w;
#pragma unroll
            for (int u = 0; u < 8; ++u) {
                int i = g * 8 + u;
                if ((i & 1) == 0 && t < 64) {       // row i>>1, cols t*4..+3 (<256)
                    unsigned rm = rowm[i >> 1];
                    fx4 vv = v[u];
                    s += (rm & cm0) ? (1.f - 2.f * vv.x) : 0.f;   // (v-1)^2 - v^2
                    s += (rm & cm1) ? (1.f - 2.f * vv.y) : 0.f;
                    s += (rm & cm2) ? (1.f - 2.f * vv.z) : 0.f;
                    s += (rm & cm3) ? (1.f - 2.f * vv.w) : 0.f;
                }
            }
        }
        s += ((a[0] + a[1]) + (a[2] + a[3])) + ((a[4] + a[5]) + (a[6] + a[7]));
    }

    // ---- block reduce -> one pre-scaled atomicAdd per block ----
    for (int off = 32; off > 0; off >>= 1)
        s += __shfl_down(s, off, 64);
    __shared__ float wsum[4];
    if ((t & 63) == 0) wsum[t >> 6] = s;
    __syncthreads();
    if (t == 0) {
        float tot = wsum[0] + wsum[1] + wsum[2] + wsum[3];
        atomicAdd(out, tot * (1.0f / (float)TOTAL_F));
    }
}

extern "C" void kernel_launch(void* const* d_in, const int* in_sizes, int n_in,
                              void* d_out, int out_size, void* d_ws, size_t ws_size,
                              hipStream_t stream) {
    const float* raw_scores = (const float*)d_in[0];
    const int*   cluster_sz = (const int*)d_in[1];
    float* out = (float*)d_out;

    hipMemsetAsync(out, 0, sizeof(float), stream);   // graph-legal memset node
    k_main<<<NBLK, 256, 0, stream>>>(raw_scores, cluster_sz, out);
}

// Round 8
// 46.595 us; speedup vs baseline: 1.1752x; 1.1752x over previous
//
#include <hip/hip_runtime.h>

#define NV 2048
#define BS 16
#define NC 16

#define TOTAL_F 67108864LL          // 16 * 2048 * 2048
#define NBLK 2048
#define F4_PER_BLOCK 8192           // contiguous float4s per block (128 KB = 16 rows)

typedef float fx4 __attribute__((ext_vector_type(4)));

// Block bid covers batch (bid>>7), rows (bid&127)*16 .. +16, all 2048 cols.
// Iteration i covers row (i>>1), half (i&1): cols [(i&1)*1024 + t*4 ..+4).
// Corner (target can be 1): rows<256 -> (bid&127)<16; cols<256 -> i even, t<64.
//
// Structure: k_main streams 268.4 MB at the ~6.25 TB/s read ceiling (99% of
// the 6.29 TB/s measured ceiling), corner correction computed inline from
// already-loaded registers (zero re-read). k_final = 1 wave. Fusion via
// graph memset node costs +8 us (R7); cross-replay L3 reuse impossible
// (harness restore-fills scrub the 256 MiB Infinity Cache between replays).

__global__ __launch_bounds__(256) void k_main(const float* __restrict__ x,
                                              const int* __restrict__ cs,
                                              float* __restrict__ partial) {
    int bid = blockIdx.x;
    int t = threadIdx.x;
    const fx4* x4 = (const fx4*)x + (long long)bid * F4_PER_BLOCK;

    bool corner = (bid & 127) < 16;
    float s = 0.f;

    if (!corner) {
        // ---- pure stream: 8-deep load batches, 8 independent accumulators ----
        float a[8] = {0.f, 0.f, 0.f, 0.f, 0.f, 0.f, 0.f, 0.f};
#pragma unroll
        for (int g = 0; g < 4; ++g) {
            fx4 v[8];
#pragma unroll
            for (int u = 0; u < 8; ++u)
                v[u] = x4[(g * 8 + u) * 256 + t];
#pragma unroll
            for (int u = 0; u < 8; ++u)
                a[u] += v[u].x * v[u].x + v[u].y * v[u].y + v[u].z * v[u].z + v[u].w * v[u].w;
        }
        s = ((a[0] + a[1]) + (a[2] + a[3])) + ((a[4] + a[5]) + (a[6] + a[7]));
    } else {
        // ---- corner block: stream + inline correction from registers ----
        int b = bid >> 7;
        int r0 = (bid & 127) << 4;              // < 256
        __shared__ int st_[NC], en_[NC];
        __shared__ unsigned rowm[16];
        if (t < NC) {
            int sz = cs[b * NC + t];
            int st = (t == 0) ? 0 : cs[b * NC + t - 1];  // start_k = n_{k-1} (NOT cumulative)
            st_[t] = st;
            en_[t] = st + sz;
        }
        __syncthreads();
        if (t < 16) {
            int r = r0 + t;
            unsigned m = 0;
#pragma unroll
            for (int k = 0; k < NC; ++k)
                if (r >= st_[k] && r < en_[k]) m |= 1u << k;
            rowm[t] = m;
        }
        unsigned cm0 = 0, cm1 = 0, cm2 = 0, cm3 = 0;
        if (t < 64) {
            int c = t * 4;
#pragma unroll
            for (int k = 0; k < NC; ++k) {
                int st = st_[k], en = en_[k];
                if (c     >= st && c     < en) cm0 |= 1u << k;
                if (c + 1 >= st && c + 1 < en) cm1 |= 1u << k;
                if (c + 2 >= st && c + 2 < en) cm2 |= 1u << k;
                if (c + 3 >= st && c + 3 < en) cm3 |= 1u << k;
            }
        }
        __syncthreads();

        float a[8] = {0.f, 0.f, 0.f, 0.f, 0.f, 0.f, 0.f, 0.f};
#pragma unroll
        for (int g = 0; g < 4; ++g) {
            fx4 v[8];
#pragma unroll
            for (int u = 0; u < 8; ++u)
                v[u] = x4[(g * 8 + u) * 256 + t];
#pragma unroll
            for (int u = 0; u < 8; ++u)
                a[u] += v[u].x * v[u].x + v[u].y * v[u].y + v[u].z * v[u].z + v[u].w * v[u].w;
#pragma unroll
            for (int u = 0; u < 8; ++u) {
                int i = g * 8 + u;
                if ((i & 1) == 0 && t < 64) {       // row i>>1, cols t*4..+3 (<256)
                    unsigned rm = rowm[i >> 1];
                    fx4 vv = v[u];
                    s += (rm & cm0) ? (1.f - 2.f * vv.x) : 0.f;   // (v-1)^2 - v^2
                    s += (rm & cm1) ? (1.f - 2.f * vv.y) : 0.f;
                    s += (rm & cm2) ? (1.f - 2.f * vv.z) : 0.f;
                    s += (rm & cm3) ? (1.f - 2.f * vv.w) : 0.f;
                }
            }
        }
        s += ((a[0] + a[1]) + (a[2] + a[3])) + ((a[4] + a[5]) + (a[6] + a[7]));
    }

    // ---- block reduce -> one partial per block (plain store, no init needed) ----
    for (int off = 32; off > 0; off >>= 1)
        s += __shfl_down(s, off, 64);
    __shared__ float wsum[4];
    if ((t & 63) == 0) wsum[t >> 6] = s;
    __syncthreads();
    if (t == 0) partial[bid] = wsum[0] + wsum[1] + wsum[2] + wsum[3];
}

// Single wave: 2048 partials = 512 fx4 = 8 fx4 per lane. No LDS, no barrier.
__global__ __launch_bounds__(64) void k_final(const float* __restrict__ partial,
                                              float* __restrict__ out) {
    int t = threadIdx.x;
    const fx4* p4 = (const fx4*)partial;
    float s = 0.f;
#pragma unroll
    for (int i = 0; i < 8; ++i) {
        fx4 v = p4[t + i * 64];
        s += (v.x + v.y) + (v.z + v.w);
    }
    for (int off = 32; off > 0; off >>= 1)
        s += __shfl_down(s, off, 64);
    if (t == 0)
        out[0] = s * (1.0f / (float)TOTAL_F);
}

extern "C" void kernel_launch(void* const* d_in, const int* in_sizes, int n_in,
                              void* d_out, int out_size, void* d_ws, size_t ws_size,
                              hipStream_t stream) {
    const float* raw_scores = (const float*)d_in[0];
    const int*   cluster_sz = (const int*)d_in[1];
    float* out = (float*)d_out;
    float* partial = (float*)d_ws;   // NBLK floats; every slot written each call

    k_main<<<NBLK, 256, 0, stream>>>(raw_scores, cluster_sz, partial);
    k_final<<<1, 64, 0, stream>>>(partial, out);
}